// Round 10
// baseline (417.688 us; speedup 1.0000x reference)
//
#include <hip/hip_runtime.h>
#include <hip/hip_bf16.h>
#include <math.h>

// Problem constants (from reference)
#define BB 2
#define LL 2048
#define DMODEL 1024
#define DINNER 2048
#define DSTATE 16
#define DCONV 4
#define DTRANK 64
#define MROWS (BB * LL)          // 4096
#define XPROJ_N (DTRANK + 2 * DSTATE)  // 96

// scan segmentation: SEG=64; 4 lanes share one d (4 states each) ->
// grid 4096 blocks = 16384 waves = 16 waves/SIMD.
#define SEG 64
#define LS (LL / SEG)            // 32
#define DPB 64                   // d-channels per 256-thread scan block

// x_proj split-K
#define XKSPLIT 8
#define XKC (DINNER / XKSPLIT)   // 256

typedef unsigned short ushort_t;
typedef short s8v __attribute__((ext_vector_type(8)));   // 8 x bf16 (4 VGPRs)
typedef float f4v __attribute__((ext_vector_type(4)));   // 4 x fp32 acc

__device__ __forceinline__ float siluf(float x) {
    return x / (1.f + expf(-x));
}
__device__ __forceinline__ float softplusf(float x) {
    return fmaxf(x, 0.f) + log1pf(expf(-fabsf(x)));
}
__device__ __forceinline__ ushort_t f32_to_bf16(float f) {
    unsigned u = __builtin_bit_cast(unsigned, f);
    unsigned r = (u + 0x7FFFu + ((u >> 16) & 1u)) >> 16;   // RNE
    return (ushort_t)r;
}
__device__ __forceinline__ float bf16_to_f32(ushort_t u) {
    return __builtin_bit_cast(float, ((unsigned)u) << 16);
}

// -------------------------------------------------------------------------
// Fused prep: all fp32->bf16 weight/input casts + xdbl zeroing, one launch.
// -------------------------------------------------------------------------
__global__ __launch_bounds__(256) void prep_kernel(
    const float* __restrict__ x, const float* __restrict__ ipw,
    const float* __restrict__ sow, const float* __restrict__ fw,
    const float* __restrict__ xpw, const float* __restrict__ dtw,
    ushort_t* __restrict__ x_bf, ushort_t* __restrict__ ipw_bf,
    ushort_t* __restrict__ sow_bf, ushort_t* __restrict__ fw_bf,
    ushort_t* __restrict__ xpw_bf, ushort_t* __restrict__ dtw_bf,
    float4* __restrict__ xdbl_zero)
{
    const long i = ((long)blockIdx.x * 256 + threadIdx.x) * 4;
    const float* src; ushort_t* dst; long off;
    if      (i < 4194304L)  { src = x;   dst = x_bf;   off = i; }
    else if (i < 8388608L)  { src = ipw; dst = ipw_bf; off = i - 4194304L; }
    else if (i < 10485760L) { src = sow; dst = sow_bf; off = i - 8388608L; }
    else if (i < 11534336L) { src = fw;  dst = fw_bf;  off = i - 10485760L; }
    else if (i < 11730944L) { src = xpw; dst = xpw_bf; off = i - 11534336L; }
    else if (i < 11862016L) { src = dtw; dst = dtw_bf; off = i - 11730944L; }
    else { xdbl_zero[(i - 11862016L) >> 2] = make_float4(0.f, 0.f, 0.f, 0.f); return; }
    const float4 v = *reinterpret_cast<const float4*>(src + off);
    ushort_t o[4] = {f32_to_bf16(v.x), f32_to_bf16(v.y),
                     f32_to_bf16(v.z), f32_to_bf16(v.w)};
    *reinterpret_cast<uint2*>(dst + off) = *reinterpret_cast<uint2*>(o);
}

// cast xdbl[:, 0:64] (ld 96, fp32) -> dt_bf [MROWS,64]
__global__ __launch_bounds__(256) void cast_dt_kernel(
    const float* __restrict__ xdbl, ushort_t* __restrict__ dtbf)
{
    const int i4 = (blockIdx.x * 256 + threadIdx.x) * 4;   // over MROWS*64
    const int row = i4 >> 6;
    const int col = i4 & 63;
    const float4 v = *reinterpret_cast<const float4*>(&xdbl[(size_t)row * XPROJ_N + col]);
    ushort_t o[4] = {f32_to_bf16(v.x), f32_to_bf16(v.y),
                     f32_to_bf16(v.z), f32_to_bf16(v.w)};
    *reinterpret_cast<uint2*>(dtbf + i4) = *reinterpret_cast<uint2*>(o);
}

// -------------------------------------------------------------------------
// bf16 MFMA GEMM, 128x128 tile, 512 threads = 8 waves (2x4 wave grid,
// 64x32/wave, acc[4][2]). Used for in_proj (1024 blocks = 4 blocks/CU =
// 32 waves/CU -> MfmaUtil 27%, round-9). Coalesced round-3 staging.
// Split output: cols >= splitN go to C1 at (col - splitN).
// -------------------------------------------------------------------------
#define TM 128
#define TN 128
#define TBK 32

__global__ __launch_bounds__(512) void gemm_bf16_mfma(
    const ushort_t* __restrict__ A, int lda,
    const ushort_t* __restrict__ B, int ldb,
    int K,
    void* __restrict__ C0v, void* __restrict__ C1v, int splitN, int ldc,
    const float* __restrict__ bias, int act, int store_bf16)
{
    __shared__ __align__(16) ushort_t As[TM * TBK];   // 8 KB
    __shared__ __align__(16) ushort_t Bs[TN * TBK];   // 8 KB

    const int tid  = threadIdx.x;
    const int lane = tid & 63;
    const int w    = tid >> 6;            // wave 0..7
    const int wm   = w & 1;               // wave row (0..1) -> 64 rows
    const int wn   = w >> 1;              // wave col (0..3) -> 32 cols
    const int m0   = blockIdx.y * TM;
    const int n0   = blockIdx.x * TN;

    const int srow = lane >> 2;           // 0..15
    const int scol = (lane & 3) * 8;      // bf16 elems: 0,8,16,24

    f4v acc[4][2] = {};

    for (int k0 = 0; k0 < K; k0 += TBK) {
        {
            const ushort_t* ga = A + (size_t)(m0 + w * 16 + srow) * lda + k0 + scol;
            __builtin_amdgcn_global_load_lds(
                (const __attribute__((address_space(1))) unsigned int*)ga,
                (__attribute__((address_space(3))) unsigned int*)(As + w * 512),
                16, 0, 0);
        }
        {
            const ushort_t* gb = B + (size_t)(n0 + w * 16 + srow) * ldb + k0 + scol;
            __builtin_amdgcn_global_load_lds(
                (const __attribute__((address_space(1))) unsigned int*)gb,
                (__attribute__((address_space(3))) unsigned int*)(Bs + w * 512),
                16, 0, 0);
        }
        __syncthreads();

        const int fr = lane & 15;
        const int kg = lane >> 4;         // k-group 0..3 (8 elems each)
        s8v a[4], b[2];
        #pragma unroll
        for (int t = 0; t < 4; ++t)
            a[t] = *reinterpret_cast<const s8v*>(As + (wm * 64 + t * 16 + fr) * TBK + kg * 8);
        #pragma unroll
        for (int t = 0; t < 2; ++t)
            b[t] = *reinterpret_cast<const s8v*>(Bs + (wn * 32 + t * 16 + fr) * TBK + kg * 8);
        #pragma unroll
        for (int i = 0; i < 4; ++i)
            #pragma unroll
            for (int j = 0; j < 2; ++j)
                acc[i][j] = __builtin_amdgcn_mfma_f32_16x16x32_bf16(
                    a[i], b[j], acc[i][j], 0, 0, 0);
        __syncthreads();
    }

    // epilogue: C/D layout col=lane&15, row=(lane>>4)*4+reg  [m89]
    const int rbase = (lane >> 4) * 4;
    const int cbase = lane & 15;
    #pragma unroll
    for (int i = 0; i < 4; ++i) {
        #pragma unroll
        for (int j = 0; j < 2; ++j) {
            const int row = m0 + wm * 64 + i * 16 + rbase;
            const int col = n0 + wn * 32 + j * 16 + cbase;
            void* Cp = C0v;
            int c2 = col;
            if (C1v && col >= splitN) { Cp = C1v; c2 = col - splitN; }
            const float bv = bias ? bias[col] : 0.f;
            #pragma unroll
            for (int r = 0; r < 4; ++r) {
                float v = acc[i][j][r] + bv;
                if (act == 1) v = siluf(v);
                else if (act == 2) v = softplusf(v);
                if (store_bf16)
                    ((ushort_t*)Cp)[(size_t)(row + r) * ldc + c2] = f32_to_bf16(v);
                else
                    ((float*)Cp)[(size_t)(row + r) * ldc + c2] = v;
            }
        }
    }
}

// -------------------------------------------------------------------------
// 64x128-tile variant for the N<=2048 GEMMs (dt_proj/out_proj/final).
// 512 threads = 8 waves, 2x4 wave grid, 32x32/wave, acc[2][2].
// Rationale: 128x128 tile gave out_proj only 256 blocks = 1 block/CU =
// 2 waves/SIMD; 64-row tile doubles/quadruples the grid (more blocks/CU).
// -------------------------------------------------------------------------
#define UM 64
#define UN 128

__global__ __launch_bounds__(512) void gemm64_bf16_mfma(
    const ushort_t* __restrict__ A, int lda,
    const ushort_t* __restrict__ B, int ldb,
    int K,
    void* __restrict__ C0v, int ldc,
    const float* __restrict__ bias, int act, int store_bf16)
{
    __shared__ __align__(16) ushort_t As[UM * TBK];   // 4 KB
    __shared__ __align__(16) ushort_t Bs[UN * TBK];   // 8 KB

    const int tid  = threadIdx.x;
    const int lane = tid & 63;
    const int w    = tid >> 6;            // wave 0..7
    const int wm   = w & 1;               // wave row (0..1) -> 32 rows
    const int wn   = w >> 1;              // wave col (0..3) -> 32 cols
    const int m0   = blockIdx.y * UM;
    const int n0   = blockIdx.x * UN;

    const int srow = lane >> 2;
    const int scol = (lane & 3) * 8;

    f4v acc[2][2] = {};

    for (int k0 = 0; k0 < K; k0 += TBK) {
        if (w < 4) {   // A chunks 0..3 (64 rows)
            const ushort_t* ga = A + (size_t)(m0 + w * 16 + srow) * lda + k0 + scol;
            __builtin_amdgcn_global_load_lds(
                (const __attribute__((address_space(1))) unsigned int*)ga,
                (__attribute__((address_space(3))) unsigned int*)(As + w * 512),
                16, 0, 0);
        }
        {   // B chunks 0..7 (128 rows)
            const ushort_t* gb = B + (size_t)(n0 + w * 16 + srow) * ldb + k0 + scol;
            __builtin_amdgcn_global_load_lds(
                (const __attribute__((address_space(1))) unsigned int*)gb,
                (__attribute__((address_space(3))) unsigned int*)(Bs + w * 512),
                16, 0, 0);
        }
        __syncthreads();

        const int fr = lane & 15;
        const int kg = lane >> 4;
        s8v a[2], b[2];
        #pragma unroll
        for (int t = 0; t < 2; ++t)
            a[t] = *reinterpret_cast<const s8v*>(As + (wm * 32 + t * 16 + fr) * TBK + kg * 8);
        #pragma unroll
        for (int t = 0; t < 2; ++t)
            b[t] = *reinterpret_cast<const s8v*>(Bs + (wn * 32 + t * 16 + fr) * TBK + kg * 8);
        #pragma unroll
        for (int i = 0; i < 2; ++i)
            #pragma unroll
            for (int j = 0; j < 2; ++j)
                acc[i][j] = __builtin_amdgcn_mfma_f32_16x16x32_bf16(
                    a[i], b[j], acc[i][j], 0, 0, 0);
        __syncthreads();
    }

    const int rbase = (lane >> 4) * 4;
    const int cbase = lane & 15;
    #pragma unroll
    for (int i = 0; i < 2; ++i) {
        #pragma unroll
        for (int j = 0; j < 2; ++j) {
            const int row = m0 + wm * 32 + i * 16 + rbase;
            const int col = n0 + wn * 32 + j * 16 + cbase;
            const float bv = bias ? bias[col] : 0.f;
            #pragma unroll
            for (int r = 0; r < 4; ++r) {
                float v = acc[i][j][r] + bv;
                if (act == 1) v = siluf(v);
                else if (act == 2) v = softplusf(v);
                if (store_bf16)
                    ((ushort_t*)C0v)[(size_t)(row + r) * ldc + col] = f32_to_bf16(v);
                else
                    ((float*)C0v)[(size_t)(row + r) * ldc + col] = v;
            }
        }
    }
}

// -------------------------------------------------------------------------
// x_proj skinny GEMM, split-K with fp32 atomic reduction.
// -------------------------------------------------------------------------
__global__ __launch_bounds__(256) void xproj_mfma(
    const ushort_t* __restrict__ A, const ushort_t* __restrict__ Bw,
    float* __restrict__ Cout)
{
    __shared__ __align__(16) ushort_t As[64 * 32];   // 4 KB
    __shared__ __align__(16) ushort_t Bs[96 * 32];   // 6 KB

    const int tid = threadIdx.x;
    const int lane = tid & 63;
    const int w = tid >> 6;
    const int kbase = blockIdx.x * XKC;
    const int m0 = blockIdx.y * 64;

    const int srow = lane >> 2;
    const int scol = (lane & 3) * 8;

    f4v acc[6] = {};

    for (int k0 = kbase; k0 < kbase + XKC; k0 += 32) {
        {
            const ushort_t* ga = A + (size_t)(m0 + w * 16 + srow) * DINNER + k0 + scol;
            __builtin_amdgcn_global_load_lds(
                (const __attribute__((address_space(1))) unsigned int*)ga,
                (__attribute__((address_space(3))) unsigned int*)(As + (w * 16) * 32),
                16, 0, 0);
        }
        {
            const ushort_t* gb = Bw + (size_t)(w * 16 + srow) * DINNER + k0 + scol;
            __builtin_amdgcn_global_load_lds(
                (const __attribute__((address_space(1))) unsigned int*)gb,
                (__attribute__((address_space(3))) unsigned int*)(Bs + (w * 16) * 32),
                16, 0, 0);
        }
        if (w < 2) {
            const ushort_t* gb = Bw + (size_t)((4 + w) * 16 + srow) * DINNER + k0 + scol;
            __builtin_amdgcn_global_load_lds(
                (const __attribute__((address_space(1))) unsigned int*)gb,
                (__attribute__((address_space(3))) unsigned int*)(Bs + ((4 + w) * 16) * 32),
                16, 0, 0);
        }
        __syncthreads();

        const int fr = lane & 15;
        const int kg = lane >> 4;
        const s8v a = *reinterpret_cast<const s8v*>(As + (w * 16 + fr) * 32 + kg * 8);
        #pragma unroll
        for (int j = 0; j < 6; ++j) {
            const s8v b = *reinterpret_cast<const s8v*>(Bs + (j * 16 + fr) * 32 + kg * 8);
            acc[j] = __builtin_amdgcn_mfma_f32_16x16x32_bf16(a, b, acc[j], 0, 0, 0);
        }
        __syncthreads();
    }

    const int rbase = (lane >> 4) * 4;
    const int cb = lane & 15;
    #pragma unroll
    for (int j = 0; j < 6; ++j)
        #pragma unroll
        for (int r = 0; r < 4; ++r)
            atomicAdd(&Cout[(size_t)(m0 + w * 16 + rbase + r) * XPROJ_N + j * 16 + cb],
                      acc[j][r]);
}

// -------------------------------------------------------------------------
// Causal depthwise conv1d (W=4) + bias + SiLU; bf16 in, bf16 out.
// -------------------------------------------------------------------------
__global__ __launch_bounds__(256) void conv_silu_kernel(
    const ushort_t* __restrict__ xin, const float* __restrict__ w,
    const float* __restrict__ b, ushort_t* __restrict__ xcbf)
{
    const int idx = blockIdx.x * blockDim.x + threadIdx.x;
    const int c = idx % DINNER;
    const int bl = idx / DINNER;
    const int l = bl % LL;
    const int bb = bl / LL;
    if (bb >= BB) return;

    const ushort_t* xp = xin + (size_t)bb * LL * DINNER + c;
    float acc = b[c];
    #pragma unroll
    for (int k = 0; k < DCONV; ++k) {
        const int ll = l - (DCONV - 1) + k;
        if (ll >= 0)
            acc = fmaf(bf16_to_f32(xp[(size_t)ll * DINNER]), w[c * DCONV + k], acc);
    }
    xcbf[idx] = f32_to_bf16(siluf(acc));
}

// -------------------------------------------------------------------------
// Segmented selective scan, SEG=64, 4 states/thread (4 lanes per d).
// Grid (DINNER/DPB, SEG, BB) = 4096 blocks = 16 waves/SIMD.
// -------------------------------------------------------------------------
__global__ __launch_bounds__(256) void scan_part1(
    const ushort_t* __restrict__ delta, const float* __restrict__ xdbl,
    const ushort_t* __restrict__ xc, const float* __restrict__ A_log,
    float* __restrict__ hloc, float* __restrict__ decay)
{
    const int tid = threadIdx.x;
    const int nsub = tid & 3;                      // state group 0..3
    const int d = blockIdx.x * DPB + (tid >> 2);
    const int seg = blockIdx.y;
    const int b = blockIdx.z;
    const int t0 = seg * LS;

    float Ad[4];
    #pragma unroll
    for (int i = 0; i < 4; ++i)
        Ad[i] = -expf(A_log[d * DSTATE + nsub * 4 + i]);

    float h[4] = {};

    const ushort_t* dp = delta + ((size_t)b * LL) * DINNER + d;
    const ushort_t* up = xc    + ((size_t)b * LL) * DINNER + d;
    const float*    xb = xdbl  + ((size_t)b * LL) * XPROJ_N;

    float sum_dl = 0.f;
    for (int t = t0; t < t0 + LS; ++t) {
        const float dl = bf16_to_f32(dp[(size_t)t * DINNER]);
        const float u  = bf16_to_f32(up[(size_t)t * DINNER]);
        const float4 Bv = *reinterpret_cast<const float4*>(
            &xb[t * XPROJ_N + DTRANK + nsub * 4]);
        const float bv[4] = {Bv.x, Bv.y, Bv.z, Bv.w};
        const float dlu = dl * u;
        sum_dl += dl;
        #pragma unroll
        for (int i = 0; i < 4; ++i)
            h[i] = __expf(dl * Ad[i]) * h[i] + dlu * bv[i];
    }

    const size_t base = (((size_t)b * SEG + seg) * DSTATE + nsub * 4) * DINNER + d;
    #pragma unroll
    for (int i = 0; i < 4; ++i) {
        hloc[base + (size_t)i * DINNER]  = h[i];
        decay[base + (size_t)i * DINNER] = __expf(Ad[i] * sum_dl);
    }
}

// In-place combine: hloc[s] is REPLACED by the true h_start of segment s.
__global__ __launch_bounds__(256) void scan_combine(
    float* __restrict__ hloc, const float* __restrict__ decay)
{
    const int idx = blockIdx.x * 256 + threadIdx.x;
    const int d = idx % DINNER;
    const int n = (idx / DINNER) % DSTATE;
    const int b = idx / (DINNER * DSTATE);
    if (b >= BB) return;

    float carry = 0.f;
    for (int s = 0; s < SEG; ++s) {
        const size_t off = (((size_t)b * SEG + s) * DSTATE + n) * DINNER + d;
        const float hl = hloc[off];
        hloc[off] = carry;
        carry = decay[off] * carry + hl;
    }
}

__global__ __launch_bounds__(256) void scan_part2(
    const ushort_t* __restrict__ delta, const float* __restrict__ xdbl,
    const ushort_t* __restrict__ xc, const ushort_t* __restrict__ z,
    const float* __restrict__ A_log, const float* __restrict__ Dvec,
    const float* __restrict__ hstart, ushort_t* __restrict__ ybf)
{
    const int tid = threadIdx.x;
    const int nsub = tid & 3;
    const int d = blockIdx.x * DPB + (tid >> 2);
    const int seg = blockIdx.y;
    const int b = blockIdx.z;
    const int t0 = seg * LS;

    float Ad[4];
    #pragma unroll
    for (int i = 0; i < 4; ++i)
        Ad[i] = -expf(A_log[d * DSTATE + nsub * 4 + i]);

    float h[4];
    const size_t hbase = (((size_t)b * SEG + seg) * DSTATE + nsub * 4) * DINNER + d;
    #pragma unroll
    for (int i = 0; i < 4; ++i)
        h[i] = hstart[hbase + (size_t)i * DINNER];

    const float Dd = Dvec[d];
    const ushort_t* dp = delta + ((size_t)b * LL) * DINNER + d;
    const ushort_t* up = xc    + ((size_t)b * LL) * DINNER + d;
    const float*    xb = xdbl  + ((size_t)b * LL) * XPROJ_N;
    const ushort_t* zp = z     + ((size_t)b * LL) * DINNER + d;
    ushort_t*       yp = ybf   + ((size_t)b * LL) * DINNER + d;

    for (int t = t0; t < t0 + LS; ++t) {
        const float dl = bf16_to_f32(dp[(size_t)t * DINNER]);
        const float u  = bf16_to_f32(up[(size_t)t * DINNER]);
        const float zv = bf16_to_f32(zp[(size_t)t * DINNER]);
        const float4 Bv = *reinterpret_cast<const float4*>(
            &xb[t * XPROJ_N + DTRANK + nsub * 4]);
        const float4 Cv = *reinterpret_cast<const float4*>(
            &xb[t * XPROJ_N + DTRANK + DSTATE + nsub * 4]);
        const float bv[4] = {Bv.x, Bv.y, Bv.z, Bv.w};
        const float cv[4] = {Cv.x, Cv.y, Cv.z, Cv.w};
        const float dlu = dl * u;
        float y = 0.f;
        #pragma unroll
        for (int i = 0; i < 4; ++i) {
            h[i] = __expf(dl * Ad[i]) * h[i] + dlu * bv[i];
            y = fmaf(h[i], cv[i], y);
        }
        // reduce across the 4 lanes sharing this d (lanes l, l^1, l^2)
        y += __shfl_xor(y, 1);
        y += __shfl_xor(y, 2);
        if (nsub == 0)
            yp[(size_t)t * DINNER] = f32_to_bf16((y + u * Dd) * siluf(zv));
    }
}

// -------------------------------------------------------------------------
extern "C" void kernel_launch(void* const* d_in, const int* in_sizes, int n_in,
                              void* d_out, int out_size, void* d_ws, size_t ws_size,
                              hipStream_t stream) {
    const float* x         = (const float*)d_in[0];
    const float* in_proj_w = (const float*)d_in[1];
    const float* conv_w    = (const float*)d_in[2];
    const float* conv_b    = (const float*)d_in[3];
    const float* x_proj_w  = (const float*)d_in[4];
    const float* dt_proj_w = (const float*)d_in[5];
    const float* dt_proj_b = (const float*)d_in[6];
    const float* A_log     = (const float*)d_in[7];
    const float* Dvec      = (const float*)d_in[8];
    const float* ssm_out_w = (const float*)d_in[9];
    const float* final_w   = (const float*)d_in[10];
    const float* final_b   = (const float*)d_in[11];
    float* out = (float*)d_out;

    // ---- workspace layout, 126 MB total ----
    const size_t MB = 1024 * 1024;
    char* base = (char*)d_ws;
    ushort_t* xin_bf   = (ushort_t*)(base);              // 16 MB [in_proj -> conv]
    ushort_t* z_bf     = (ushort_t*)(base + 16 * MB);    // 16 MB [in_proj -> scan2]
    ushort_t* xc_bf    = (ushort_t*)(base + 32 * MB);    // 16 MB [conv -> xproj/scan]
    ushort_t* delta_bf = (ushort_t*)(base + 48 * MB);    // 16 MB [dt_proj -> scan]
    float*    xdbl     = (float*)(base + 64 * MB);       // 1.5 MB [xproj -> scan]
    ushort_t* x_bf     = (ushort_t*)(base + 78 * MB);    // 8 MB [prep -> in_proj]
    ushort_t* ipw_bf   = (ushort_t*)(base + 86 * MB);    // 8 MB [prep -> in_proj]
    ushort_t* sow_bf   = (ushort_t*)(base + 94 * MB);    // 4 MB
    ushort_t* fw_bf    = (ushort_t*)(base + 98 * MB);    // 2 MB
    ushort_t* xpw_bf   = (ushort_t*)(base + 100 * MB);   // 384 KB
    ushort_t* dtw_bf   = (ushort_t*)(base + 100 * MB + 512 * 1024);  // 256 KB
    ushort_t* dt_bf    = (ushort_t*)(base + 101 * MB);   // 512 KB
    ushort_t* y_bf     = (ushort_t*)(base + 102 * MB);   // 16 MB
    ushort_t* outb_bf  = (ushort_t*)(base + 118 * MB);   // 8 MB
    // scan scratch (16 MB each), OVERLAID on dead regions:
    float* hloc  = (float*)(base);            // 16 MB over xin_bf (dead after conv)
    float* decay = (float*)(base + 78 * MB);  // 16 MB over x_bf/ipw_bf (dead after in_proj)

    // 0) fused casts + xdbl zeroing (one launch; 11968 blocks)
    prep_kernel<<<11968, 256, 0, stream>>>(
        x, in_proj_w, ssm_out_w, final_w, x_proj_w, dt_proj_w,
        x_bf, ipw_bf, sow_bf, fw_bf, xpw_bf, dtw_bf, (float4*)xdbl);

    // 1) in_proj (bf16 MFMA): [xin_bf | z_bf] = x @ in_proj_w^T  (M=4096,N=4096,K=1024)
    gemm_bf16_mfma<<<dim3(2 * DINNER / TN, MROWS / TM), 512, 0, stream>>>(
        x_bf, DMODEL, ipw_bf, DMODEL, DMODEL,
        xin_bf, z_bf, DINNER, DINNER, nullptr, 0, 1);

    // 2) causal depthwise conv + SiLU -> xc_bf
    conv_silu_kernel<<<(MROWS * DINNER) / 256, 256, 0, stream>>>(
        xin_bf, conv_w, conv_b, xc_bf);

    // 3) x_proj (bf16 MFMA, split-K atomic): xdbl = xc @ x_proj_w^T (M=4096,N=96,K=2048)
    xproj_mfma<<<dim3(XKSPLIT, MROWS / 64), 256, 0, stream>>>(xc_bf, xpw_bf, xdbl);

    // 4) dt_proj (bf16 MFMA, 64-row tile): delta_bf = softplus(dt @ dt_proj_w^T + b)
    cast_dt_kernel<<<(MROWS * DTRANK / 4) / 256, 256, 0, stream>>>(xdbl, dt_bf);
    gemm64_bf16_mfma<<<dim3(DINNER / UN, MROWS / UM), 512, 0, stream>>>(
        dt_bf, DTRANK, dtw_bf, DTRANK, DTRANK,
        delta_bf, DINNER, dt_proj_b, 2, 1);

    // 5) segmented selective scan + skip + gate -> y_bf
    scan_part1<<<dim3(DINNER / DPB, SEG, BB), 256, 0, stream>>>(
        delta_bf, xdbl, xc_bf, A_log, hloc, decay);
    scan_combine<<<(BB * DSTATE * DINNER) / 256, 256, 0, stream>>>(hloc, decay);
    scan_part2<<<dim3(DINNER / DPB, SEG, BB), 256, 0, stream>>>(
        delta_bf, xdbl, xc_bf, z_bf, A_log, Dvec, hloc, y_bf);

    // 6) out_proj (bf16 MFMA, 64-row tile): outb_bf = y @ ssm_out_w^T (M=4096,N=1024,K=2048)
    gemm64_bf16_mfma<<<dim3(DMODEL / UN, MROWS / UM), 512, 0, stream>>>(
        y_bf, DINNER, sow_bf, DINNER, DINNER,
        outb_bf, DMODEL, nullptr, 0, 1);

    // 7) final (bf16 MFMA, 64-row tile): out = silu(outb @ final_w^T + final_b)
    gemm64_bf16_mfma<<<dim3(DMODEL / UN, MROWS / UM), 512, 0, stream>>>(
        outb_bf, DMODEL, fw_bf, DMODEL, DMODEL,
        out, DMODEL, final_b, 1, 0);
}

// Round 11
// 378.916 us; speedup vs baseline: 1.1023x; 1.1023x over previous
//
#include <hip/hip_runtime.h>
#include <hip/hip_bf16.h>
#include <math.h>

// Problem constants (from reference)
#define BB 2
#define LL 2048
#define DMODEL 1024
#define DINNER 2048
#define DSTATE 16
#define DCONV 4
#define DTRANK 64
#define MROWS (BB * LL)          // 4096
#define XPROJ_N (DTRANK + 2 * DSTATE)  // 96

// scan segmentation: SEG=64, 16 states/thread, 1024 blocks = 4 waves/SIMD.
// (Round-9's 4-lane state split hit VALU-issue bound: 4x replicated scalar
//  overhead, VALUBusy 86%, 80us. Round-6's SEG=16 was latency-bound at 1
//  wave/SIMD. This config is the measured sweet spot.)
#define SEG 64
#define LS (LL / SEG)            // 32

// x_proj split-K
#define XKSPLIT 8
#define XKC (DINNER / XKSPLIT)   // 256

typedef unsigned short ushort_t;
typedef short s8v __attribute__((ext_vector_type(8)));   // 8 x bf16 (4 VGPRs)
typedef float f4v __attribute__((ext_vector_type(4)));   // 4 x fp32 acc

__device__ __forceinline__ float siluf(float x) {
    return x / (1.f + expf(-x));
}
__device__ __forceinline__ float softplusf(float x) {
    return fmaxf(x, 0.f) + log1pf(expf(-fabsf(x)));
}
__device__ __forceinline__ ushort_t f32_to_bf16(float f) {
    unsigned u = __builtin_bit_cast(unsigned, f);
    unsigned r = (u + 0x7FFFu + ((u >> 16) & 1u)) >> 16;   // RNE
    return (ushort_t)r;
}
__device__ __forceinline__ float bf16_to_f32(ushort_t u) {
    return __builtin_bit_cast(float, ((unsigned)u) << 16);
}

// -------------------------------------------------------------------------
// Fused prep: all fp32->bf16 weight/input casts + xdbl zeroing, one launch.
// -------------------------------------------------------------------------
__global__ __launch_bounds__(256) void prep_kernel(
    const float* __restrict__ x, const float* __restrict__ ipw,
    const float* __restrict__ sow, const float* __restrict__ fw,
    const float* __restrict__ xpw, const float* __restrict__ dtw,
    ushort_t* __restrict__ x_bf, ushort_t* __restrict__ ipw_bf,
    ushort_t* __restrict__ sow_bf, ushort_t* __restrict__ fw_bf,
    ushort_t* __restrict__ xpw_bf, ushort_t* __restrict__ dtw_bf,
    float4* __restrict__ xdbl_zero)
{
    const long i = ((long)blockIdx.x * 256 + threadIdx.x) * 4;
    const float* src; ushort_t* dst; long off;
    if      (i < 4194304L)  { src = x;   dst = x_bf;   off = i; }
    else if (i < 8388608L)  { src = ipw; dst = ipw_bf; off = i - 4194304L; }
    else if (i < 10485760L) { src = sow; dst = sow_bf; off = i - 8388608L; }
    else if (i < 11534336L) { src = fw;  dst = fw_bf;  off = i - 10485760L; }
    else if (i < 11730944L) { src = xpw; dst = xpw_bf; off = i - 11534336L; }
    else if (i < 11862016L) { src = dtw; dst = dtw_bf; off = i - 11730944L; }
    else { xdbl_zero[(i - 11862016L) >> 2] = make_float4(0.f, 0.f, 0.f, 0.f); return; }
    const float4 v = *reinterpret_cast<const float4*>(src + off);
    ushort_t o[4] = {f32_to_bf16(v.x), f32_to_bf16(v.y),
                     f32_to_bf16(v.z), f32_to_bf16(v.w)};
    *reinterpret_cast<uint2*>(dst + off) = *reinterpret_cast<uint2*>(o);
}

// cast xdbl[:, 0:64] (ld 96, fp32) -> dt_bf [MROWS,64]
__global__ __launch_bounds__(256) void cast_dt_kernel(
    const float* __restrict__ xdbl, ushort_t* __restrict__ dtbf)
{
    const int i4 = (blockIdx.x * 256 + threadIdx.x) * 4;   // over MROWS*64
    const int row = i4 >> 6;
    const int col = i4 & 63;
    const float4 v = *reinterpret_cast<const float4*>(&xdbl[(size_t)row * XPROJ_N + col]);
    ushort_t o[4] = {f32_to_bf16(v.x), f32_to_bf16(v.y),
                     f32_to_bf16(v.z), f32_to_bf16(v.w)};
    *reinterpret_cast<uint2*>(dtbf + i4) = *reinterpret_cast<uint2*>(o);
}

// -------------------------------------------------------------------------
// bf16 MFMA GEMM, 128x128 tile, 512 threads = 8 waves (2x4 wave grid,
// 64x32/wave, acc[4][2]). Used for in_proj (1024 blocks = 4 blocks/CU =
// 32 waves/CU -> MfmaUtil 27%, round-9). Coalesced round-3 staging.
// Split output: cols >= splitN go to C1 at (col - splitN).
// -------------------------------------------------------------------------
#define TM 128
#define TN 128
#define TBK 32

__global__ __launch_bounds__(512) void gemm_bf16_mfma(
    const ushort_t* __restrict__ A, int lda,
    const ushort_t* __restrict__ B, int ldb,
    int K,
    void* __restrict__ C0v, void* __restrict__ C1v, int splitN, int ldc,
    const float* __restrict__ bias, int act, int store_bf16)
{
    __shared__ __align__(16) ushort_t As[TM * TBK];   // 8 KB
    __shared__ __align__(16) ushort_t Bs[TN * TBK];   // 8 KB

    const int tid  = threadIdx.x;
    const int lane = tid & 63;
    const int w    = tid >> 6;            // wave 0..7
    const int wm   = w & 1;               // wave row (0..1) -> 64 rows
    const int wn   = w >> 1;              // wave col (0..3) -> 32 cols
    const int m0   = blockIdx.y * TM;
    const int n0   = blockIdx.x * TN;

    const int srow = lane >> 2;           // 0..15
    const int scol = (lane & 3) * 8;      // bf16 elems: 0,8,16,24

    f4v acc[4][2] = {};

    for (int k0 = 0; k0 < K; k0 += TBK) {
        {
            const ushort_t* ga = A + (size_t)(m0 + w * 16 + srow) * lda + k0 + scol;
            __builtin_amdgcn_global_load_lds(
                (const __attribute__((address_space(1))) unsigned int*)ga,
                (__attribute__((address_space(3))) unsigned int*)(As + w * 512),
                16, 0, 0);
        }
        {
            const ushort_t* gb = B + (size_t)(n0 + w * 16 + srow) * ldb + k0 + scol;
            __builtin_amdgcn_global_load_lds(
                (const __attribute__((address_space(1))) unsigned int*)gb,
                (__attribute__((address_space(3))) unsigned int*)(Bs + w * 512),
                16, 0, 0);
        }
        __syncthreads();

        const int fr = lane & 15;
        const int kg = lane >> 4;         // k-group 0..3 (8 elems each)
        s8v a[4], b[2];
        #pragma unroll
        for (int t = 0; t < 4; ++t)
            a[t] = *reinterpret_cast<const s8v*>(As + (wm * 64 + t * 16 + fr) * TBK + kg * 8);
        #pragma unroll
        for (int t = 0; t < 2; ++t)
            b[t] = *reinterpret_cast<const s8v*>(Bs + (wn * 32 + t * 16 + fr) * TBK + kg * 8);
        #pragma unroll
        for (int i = 0; i < 4; ++i)
            #pragma unroll
            for (int j = 0; j < 2; ++j)
                acc[i][j] = __builtin_amdgcn_mfma_f32_16x16x32_bf16(
                    a[i], b[j], acc[i][j], 0, 0, 0);
        __syncthreads();
    }

    // epilogue: C/D layout col=lane&15, row=(lane>>4)*4+reg  [m89]
    const int rbase = (lane >> 4) * 4;
    const int cbase = lane & 15;
    #pragma unroll
    for (int i = 0; i < 4; ++i) {
        #pragma unroll
        for (int j = 0; j < 2; ++j) {
            const int row = m0 + wm * 64 + i * 16 + rbase;
            const int col = n0 + wn * 32 + j * 16 + cbase;
            void* Cp = C0v;
            int c2 = col;
            if (C1v && col >= splitN) { Cp = C1v; c2 = col - splitN; }
            const float bv = bias ? bias[col] : 0.f;
            #pragma unroll
            for (int r = 0; r < 4; ++r) {
                float v = acc[i][j][r] + bv;
                if (act == 1) v = siluf(v);
                else if (act == 2) v = softplusf(v);
                if (store_bf16)
                    ((ushort_t*)Cp)[(size_t)(row + r) * ldc + c2] = f32_to_bf16(v);
                else
                    ((float*)Cp)[(size_t)(row + r) * ldc + c2] = v;
            }
        }
    }
}

// -------------------------------------------------------------------------
// 64x128-tile variant for the N<=2048 GEMMs (dt_proj/out_proj/final).
// 512 threads = 8 waves, 2x4 wave grid, 32x32/wave, acc[2][2].
// -------------------------------------------------------------------------
#define UM 64
#define UN 128

__global__ __launch_bounds__(512) void gemm64_bf16_mfma(
    const ushort_t* __restrict__ A, int lda,
    const ushort_t* __restrict__ B, int ldb,
    int K,
    void* __restrict__ C0v, int ldc,
    const float* __restrict__ bias, int act, int store_bf16)
{
    __shared__ __align__(16) ushort_t As[UM * TBK];   // 4 KB
    __shared__ __align__(16) ushort_t Bs[UN * TBK];   // 8 KB

    const int tid  = threadIdx.x;
    const int lane = tid & 63;
    const int w    = tid >> 6;            // wave 0..7
    const int wm   = w & 1;               // wave row (0..1) -> 32 rows
    const int wn   = w >> 1;              // wave col (0..3) -> 32 cols
    const int m0   = blockIdx.y * UM;
    const int n0   = blockIdx.x * UN;

    const int srow = lane >> 2;
    const int scol = (lane & 3) * 8;

    f4v acc[2][2] = {};

    for (int k0 = 0; k0 < K; k0 += TBK) {
        if (w < 4) {   // A chunks 0..3 (64 rows)
            const ushort_t* ga = A + (size_t)(m0 + w * 16 + srow) * lda + k0 + scol;
            __builtin_amdgcn_global_load_lds(
                (const __attribute__((address_space(1))) unsigned int*)ga,
                (__attribute__((address_space(3))) unsigned int*)(As + w * 512),
                16, 0, 0);
        }
        {   // B chunks 0..7 (128 rows)
            const ushort_t* gb = B + (size_t)(n0 + w * 16 + srow) * ldb + k0 + scol;
            __builtin_amdgcn_global_load_lds(
                (const __attribute__((address_space(1))) unsigned int*)gb,
                (__attribute__((address_space(3))) unsigned int*)(Bs + w * 512),
                16, 0, 0);
        }
        __syncthreads();

        const int fr = lane & 15;
        const int kg = lane >> 4;
        s8v a[2], b[2];
        #pragma unroll
        for (int t = 0; t < 2; ++t)
            a[t] = *reinterpret_cast<const s8v*>(As + (wm * 32 + t * 16 + fr) * TBK + kg * 8);
        #pragma unroll
        for (int t = 0; t < 2; ++t)
            b[t] = *reinterpret_cast<const s8v*>(Bs + (wn * 32 + t * 16 + fr) * TBK + kg * 8);
        #pragma unroll
        for (int i = 0; i < 2; ++i)
            #pragma unroll
            for (int j = 0; j < 2; ++j)
                acc[i][j] = __builtin_amdgcn_mfma_f32_16x16x32_bf16(
                    a[i], b[j], acc[i][j], 0, 0, 0);
        __syncthreads();
    }

    const int rbase = (lane >> 4) * 4;
    const int cbase = lane & 15;
    #pragma unroll
    for (int i = 0; i < 2; ++i) {
        #pragma unroll
        for (int j = 0; j < 2; ++j) {
            const int row = m0 + wm * 32 + i * 16 + rbase;
            const int col = n0 + wn * 32 + j * 16 + cbase;
            const float bv = bias ? bias[col] : 0.f;
            #pragma unroll
            for (int r = 0; r < 4; ++r) {
                float v = acc[i][j][r] + bv;
                if (act == 1) v = siluf(v);
                else if (act == 2) v = softplusf(v);
                if (store_bf16)
                    ((ushort_t*)C0v)[(size_t)(row + r) * ldc + col] = f32_to_bf16(v);
                else
                    ((float*)C0v)[(size_t)(row + r) * ldc + col] = v;
            }
        }
    }
}

// -------------------------------------------------------------------------
// x_proj skinny GEMM, split-K with fp32 atomic reduction.
// -------------------------------------------------------------------------
__global__ __launch_bounds__(256) void xproj_mfma(
    const ushort_t* __restrict__ A, const ushort_t* __restrict__ Bw,
    float* __restrict__ Cout)
{
    __shared__ __align__(16) ushort_t As[64 * 32];   // 4 KB
    __shared__ __align__(16) ushort_t Bs[96 * 32];   // 6 KB

    const int tid = threadIdx.x;
    const int lane = tid & 63;
    const int w = tid >> 6;
    const int kbase = blockIdx.x * XKC;
    const int m0 = blockIdx.y * 64;

    const int srow = lane >> 2;
    const int scol = (lane & 3) * 8;

    f4v acc[6] = {};

    for (int k0 = kbase; k0 < kbase + XKC; k0 += 32) {
        {
            const ushort_t* ga = A + (size_t)(m0 + w * 16 + srow) * DINNER + k0 + scol;
            __builtin_amdgcn_global_load_lds(
                (const __attribute__((address_space(1))) unsigned int*)ga,
                (__attribute__((address_space(3))) unsigned int*)(As + (w * 16) * 32),
                16, 0, 0);
        }
        {
            const ushort_t* gb = Bw + (size_t)(w * 16 + srow) * DINNER + k0 + scol;
            __builtin_amdgcn_global_load_lds(
                (const __attribute__((address_space(1))) unsigned int*)gb,
                (__attribute__((address_space(3))) unsigned int*)(Bs + (w * 16) * 32),
                16, 0, 0);
        }
        if (w < 2) {
            const ushort_t* gb = Bw + (size_t)((4 + w) * 16 + srow) * DINNER + k0 + scol;
            __builtin_amdgcn_global_load_lds(
                (const __attribute__((address_space(1))) unsigned int*)gb,
                (__attribute__((address_space(3))) unsigned int*)(Bs + ((4 + w) * 16) * 32),
                16, 0, 0);
        }
        __syncthreads();

        const int fr = lane & 15;
        const int kg = lane >> 4;
        const s8v a = *reinterpret_cast<const s8v*>(As + (w * 16 + fr) * 32 + kg * 8);
        #pragma unroll
        for (int j = 0; j < 6; ++j) {
            const s8v b = *reinterpret_cast<const s8v*>(Bs + (j * 16 + fr) * 32 + kg * 8);
            acc[j] = __builtin_amdgcn_mfma_f32_16x16x32_bf16(a, b, acc[j], 0, 0, 0);
        }
        __syncthreads();
    }

    const int rbase = (lane >> 4) * 4;
    const int cb = lane & 15;
    #pragma unroll
    for (int j = 0; j < 6; ++j)
        #pragma unroll
        for (int r = 0; r < 4; ++r)
            atomicAdd(&Cout[(size_t)(m0 + w * 16 + rbase + r) * XPROJ_N + j * 16 + cb],
                      acc[j][r]);
}

// -------------------------------------------------------------------------
// Causal depthwise conv1d (W=4) + bias + SiLU; bf16 in, bf16 out.
// -------------------------------------------------------------------------
__global__ __launch_bounds__(256) void conv_silu_kernel(
    const ushort_t* __restrict__ xin, const float* __restrict__ w,
    const float* __restrict__ b, ushort_t* __restrict__ xcbf)
{
    const int idx = blockIdx.x * blockDim.x + threadIdx.x;
    const int c = idx % DINNER;
    const int bl = idx / DINNER;
    const int l = bl % LL;
    const int bb = bl / LL;
    if (bb >= BB) return;

    const ushort_t* xp = xin + (size_t)bb * LL * DINNER + c;
    float acc = b[c];
    #pragma unroll
    for (int k = 0; k < DCONV; ++k) {
        const int ll = l - (DCONV - 1) + k;
        if (ll >= 0)
            acc = fmaf(bf16_to_f32(xp[(size_t)ll * DINNER]), w[c * DCONV + k], acc);
    }
    xcbf[idx] = f32_to_bf16(siluf(acc));
}

// -------------------------------------------------------------------------
// Segmented selective scan, SEG=64, 16 states/thread (round-8 form).
// Grid (DINNER/256, SEG, BB) = 1024 blocks = 4 waves/SIMD.
// B/C via converged global float4 loads (L1 broadcast).
// -------------------------------------------------------------------------
__global__ __launch_bounds__(256) void scan_part1(
    const ushort_t* __restrict__ delta, const float* __restrict__ xdbl,
    const ushort_t* __restrict__ xc, const float* __restrict__ A_log,
    float* __restrict__ hloc, float* __restrict__ decay)
{
    const int d = blockIdx.x * 256 + threadIdx.x;
    const int seg = blockIdx.y;
    const int b = blockIdx.z;
    const int t0 = seg * LS;

    float Ad[DSTATE];
    #pragma unroll
    for (int n = 0; n < DSTATE; ++n)
        Ad[n] = -expf(A_log[d * DSTATE + n]);

    float h[DSTATE];
    #pragma unroll
    for (int n = 0; n < DSTATE; ++n) h[n] = 0.f;

    const ushort_t* dp = delta + ((size_t)b * LL) * DINNER + d;
    const ushort_t* up = xc    + ((size_t)b * LL) * DINNER + d;
    const float*    xb = xdbl  + ((size_t)b * LL) * XPROJ_N;

    float sum_dl = 0.f;
    for (int t = t0; t < t0 + LS; ++t) {
        const float dl = bf16_to_f32(dp[(size_t)t * DINNER]);
        const float u  = bf16_to_f32(up[(size_t)t * DINNER]);
        const float4 b0 = *reinterpret_cast<const float4*>(&xb[t * XPROJ_N + DTRANK + 0]);
        const float4 b1 = *reinterpret_cast<const float4*>(&xb[t * XPROJ_N + DTRANK + 4]);
        const float4 b2 = *reinterpret_cast<const float4*>(&xb[t * XPROJ_N + DTRANK + 8]);
        const float4 b3 = *reinterpret_cast<const float4*>(&xb[t * XPROJ_N + DTRANK + 12]);
        const float Bv[DSTATE] = {b0.x, b0.y, b0.z, b0.w, b1.x, b1.y, b1.z, b1.w,
                                  b2.x, b2.y, b2.z, b2.w, b3.x, b3.y, b3.z, b3.w};
        const float dlu = dl * u;
        sum_dl += dl;
        #pragma unroll
        for (int n = 0; n < DSTATE; ++n)
            h[n] = __expf(dl * Ad[n]) * h[n] + dlu * Bv[n];
    }

    const size_t base = (((size_t)b * SEG + seg) * DSTATE) * DINNER + d;
    #pragma unroll
    for (int n = 0; n < DSTATE; ++n) {
        hloc[base + (size_t)n * DINNER]  = h[n];
        decay[base + (size_t)n * DINNER] = __expf(Ad[n] * sum_dl);
    }
}

// In-place combine: hloc[s] is REPLACED by the true h_start of segment s.
__global__ __launch_bounds__(256) void scan_combine(
    float* __restrict__ hloc, const float* __restrict__ decay)
{
    const int idx = blockIdx.x * 256 + threadIdx.x;
    const int d = idx % DINNER;
    const int n = (idx / DINNER) % DSTATE;
    const int b = idx / (DINNER * DSTATE);
    if (b >= BB) return;

    float carry = 0.f;
    for (int s = 0; s < SEG; ++s) {
        const size_t off = (((size_t)b * SEG + s) * DSTATE + n) * DINNER + d;
        const float hl = hloc[off];
        hloc[off] = carry;
        carry = decay[off] * carry + hl;
    }
}

__global__ __launch_bounds__(256) void scan_part2(
    const ushort_t* __restrict__ delta, const float* __restrict__ xdbl,
    const ushort_t* __restrict__ xc, const ushort_t* __restrict__ z,
    const float* __restrict__ A_log, const float* __restrict__ Dvec,
    const float* __restrict__ hstart, ushort_t* __restrict__ ybf)
{
    const int d = blockIdx.x * 256 + threadIdx.x;
    const int seg = blockIdx.y;
    const int b = blockIdx.z;
    const int t0 = seg * LS;

    float Ad[DSTATE];
    #pragma unroll
    for (int n = 0; n < DSTATE; ++n)
        Ad[n] = -expf(A_log[d * DSTATE + n]);

    float h[DSTATE];
    const size_t hbase = (((size_t)b * SEG + seg) * DSTATE) * DINNER + d;
    #pragma unroll
    for (int n = 0; n < DSTATE; ++n)
        h[n] = hstart[hbase + (size_t)n * DINNER];

    const float Dd = Dvec[d];
    const ushort_t* dp = delta + ((size_t)b * LL) * DINNER + d;
    const ushort_t* up = xc    + ((size_t)b * LL) * DINNER + d;
    const float*    xb = xdbl  + ((size_t)b * LL) * XPROJ_N;
    const ushort_t* zp = z     + ((size_t)b * LL) * DINNER + d;
    ushort_t*       yp = ybf   + ((size_t)b * LL) * DINNER + d;

    for (int t = t0; t < t0 + LS; ++t) {
        const float dl = bf16_to_f32(dp[(size_t)t * DINNER]);
        const float u  = bf16_to_f32(up[(size_t)t * DINNER]);
        const float zv = bf16_to_f32(zp[(size_t)t * DINNER]);
        const float4 b0 = *reinterpret_cast<const float4*>(&xb[t * XPROJ_N + DTRANK + 0]);
        const float4 b1 = *reinterpret_cast<const float4*>(&xb[t * XPROJ_N + DTRANK + 4]);
        const float4 b2 = *reinterpret_cast<const float4*>(&xb[t * XPROJ_N + DTRANK + 8]);
        const float4 b3 = *reinterpret_cast<const float4*>(&xb[t * XPROJ_N + DTRANK + 12]);
        const float4 c0 = *reinterpret_cast<const float4*>(&xb[t * XPROJ_N + DTRANK + DSTATE + 0]);
        const float4 c1 = *reinterpret_cast<const float4*>(&xb[t * XPROJ_N + DTRANK + DSTATE + 4]);
        const float4 c2 = *reinterpret_cast<const float4*>(&xb[t * XPROJ_N + DTRANK + DSTATE + 8]);
        const float4 c3 = *reinterpret_cast<const float4*>(&xb[t * XPROJ_N + DTRANK + DSTATE + 12]);
        const float Bv[DSTATE] = {b0.x, b0.y, b0.z, b0.w, b1.x, b1.y, b1.z, b1.w,
                                  b2.x, b2.y, b2.z, b2.w, b3.x, b3.y, b3.z, b3.w};
        const float Cv[DSTATE] = {c0.x, c0.y, c0.z, c0.w, c1.x, c1.y, c1.z, c1.w,
                                  c2.x, c2.y, c2.z, c2.w, c3.x, c3.y, c3.z, c3.w};
        const float dlu = dl * u;
        float y = 0.f;
        #pragma unroll
        for (int n = 0; n < DSTATE; ++n) {
            h[n] = __expf(dl * Ad[n]) * h[n] + dlu * Bv[n];
            y = fmaf(h[n], Cv[n], y);
        }
        yp[(size_t)t * DINNER] = f32_to_bf16((y + u * Dd) * siluf(zv));
    }
}

// -------------------------------------------------------------------------
extern "C" void kernel_launch(void* const* d_in, const int* in_sizes, int n_in,
                              void* d_out, int out_size, void* d_ws, size_t ws_size,
                              hipStream_t stream) {
    const float* x         = (const float*)d_in[0];
    const float* in_proj_w = (const float*)d_in[1];
    const float* conv_w    = (const float*)d_in[2];
    const float* conv_b    = (const float*)d_in[3];
    const float* x_proj_w  = (const float*)d_in[4];
    const float* dt_proj_w = (const float*)d_in[5];
    const float* dt_proj_b = (const float*)d_in[6];
    const float* A_log     = (const float*)d_in[7];
    const float* Dvec      = (const float*)d_in[8];
    const float* ssm_out_w = (const float*)d_in[9];
    const float* final_w   = (const float*)d_in[10];
    const float* final_b   = (const float*)d_in[11];
    float* out = (float*)d_out;

    // ---- workspace layout, 126 MB total ----
    const size_t MB = 1024 * 1024;
    char* base = (char*)d_ws;
    ushort_t* xin_bf   = (ushort_t*)(base);              // 16 MB [in_proj -> conv]
    ushort_t* z_bf     = (ushort_t*)(base + 16 * MB);    // 16 MB [in_proj -> scan2]
    ushort_t* xc_bf    = (ushort_t*)(base + 32 * MB);    // 16 MB [conv -> xproj/scan]
    ushort_t* delta_bf = (ushort_t*)(base + 48 * MB);    // 16 MB [dt_proj -> scan]
    float*    xdbl     = (float*)(base + 64 * MB);       // 1.5 MB [xproj -> scan]
    ushort_t* x_bf     = (ushort_t*)(base + 78 * MB);    // 8 MB [prep -> in_proj]
    ushort_t* ipw_bf   = (ushort_t*)(base + 86 * MB);    // 8 MB [prep -> in_proj]
    ushort_t* sow_bf   = (ushort_t*)(base + 94 * MB);    // 4 MB
    ushort_t* fw_bf    = (ushort_t*)(base + 98 * MB);    // 2 MB
    ushort_t* xpw_bf   = (ushort_t*)(base + 100 * MB);   // 384 KB
    ushort_t* dtw_bf   = (ushort_t*)(base + 100 * MB + 512 * 1024);  // 256 KB
    ushort_t* dt_bf    = (ushort_t*)(base + 101 * MB);   // 512 KB
    ushort_t* y_bf     = (ushort_t*)(base + 102 * MB);   // 16 MB
    ushort_t* outb_bf  = (ushort_t*)(base + 118 * MB);   // 8 MB
    // scan scratch (16 MB each), OVERLAID on dead regions:
    float* hloc  = (float*)(base);            // 16 MB over xin_bf (dead after conv)
    float* decay = (float*)(base + 78 * MB);  // 16 MB over x_bf/ipw_bf (dead after in_proj)

    // 0) fused casts + xdbl zeroing (one launch; 11968 blocks)
    prep_kernel<<<11968, 256, 0, stream>>>(
        x, in_proj_w, ssm_out_w, final_w, x_proj_w, dt_proj_w,
        x_bf, ipw_bf, sow_bf, fw_bf, xpw_bf, dtw_bf, (float4*)xdbl);

    // 1) in_proj (bf16 MFMA): [xin_bf | z_bf] = x @ in_proj_w^T  (M=4096,N=4096,K=1024)
    gemm_bf16_mfma<<<dim3(2 * DINNER / TN, MROWS / TM), 512, 0, stream>>>(
        x_bf, DMODEL, ipw_bf, DMODEL, DMODEL,
        xin_bf, z_bf, DINNER, DINNER, nullptr, 0, 1);

    // 2) causal depthwise conv + SiLU -> xc_bf
    conv_silu_kernel<<<(MROWS * DINNER) / 256, 256, 0, stream>>>(
        xin_bf, conv_w, conv_b, xc_bf);

    // 3) x_proj (bf16 MFMA, split-K atomic): xdbl = xc @ x_proj_w^T (M=4096,N=96,K=2048)
    xproj_mfma<<<dim3(XKSPLIT, MROWS / 64), 256, 0, stream>>>(xc_bf, xpw_bf, xdbl);

    // 4) dt_proj (bf16 MFMA, 64-row tile): delta_bf = softplus(dt @ dt_proj_w^T + b)
    cast_dt_kernel<<<(MROWS * DTRANK / 4) / 256, 256, 0, stream>>>(xdbl, dt_bf);
    gemm64_bf16_mfma<<<dim3(DINNER / UN, MROWS / UM), 512, 0, stream>>>(
        dt_bf, DTRANK, dtw_bf, DTRANK, DTRANK,
        delta_bf, DINNER, dt_proj_b, 2, 1);

    // 5) segmented selective scan + skip + gate -> y_bf
    scan_part1<<<dim3(DINNER / 256, SEG, BB), 256, 0, stream>>>(
        delta_bf, xdbl, xc_bf, A_log, hloc, decay);
    scan_combine<<<(BB * DSTATE * DINNER) / 256, 256, 0, stream>>>(hloc, decay);
    scan_part2<<<dim3(DINNER / 256, SEG, BB), 256, 0, stream>>>(
        delta_bf, xdbl, xc_bf, z_bf, A_log, Dvec, hloc, y_bf);

    // 6) out_proj (bf16 MFMA, 64-row tile): outb_bf = y @ ssm_out_w^T (M=4096,N=1024,K=2048)
    gemm64_bf16_mfma<<<dim3(DMODEL / UN, MROWS / UM), 512, 0, stream>>>(
        y_bf, DINNER, sow_bf, DINNER, DINNER,
        outb_bf, DMODEL, nullptr, 0, 1);

    // 7) final (bf16 MFMA, 64-row tile): out = silu(outb @ final_w^T + final_b)
    gemm64_bf16_mfma<<<dim3(DMODEL / UN, MROWS / UM), 512, 0, stream>>>(
        outb_bf, DMODEL, fw_bf, DMODEL, DMODEL,
        out, DMODEL, final_b, 1, 0);
}